// Round 1
// baseline (1581.016 us; speedup 1.0000x reference)
//
#include <hip/hip_runtime.h>
#include <math.h>

// Problem: energies[b,i,j] = out_state[b,i,:] . (W @ history[b,j,:] + bias)
//          out = softmax_j(energies)
// Restructured:
//   q[b,i,:] = W^T @ out_state[b,i,:]          (project the SMALL side: S_STATE=512 vs S_SEQ=2048)
//   energies[b,i,j] = q[b,i,:] . history[b,j,:] + (os[b,i].bias)
//   The bias term is constant in j -> cancels in softmax -> skipped (exact).
constexpr int B        = 64;
constexpr int S_STATE  = 512;
constexpr int S_SEQ    = 2048;
constexpr int H        = 512;

// ---------------------------------------------------------------------------
// GEMM 1 (NN): q[m][n] = sum_k OS[m][k] * W[k][n]
//   M = B*S_STATE = 32768, N = H = 512, K = H = 512
// 64x64 block tile, BK=32, 256 threads, 4x4 micro-tile.
// ---------------------------------------------------------------------------
__global__ __launch_bounds__(256) void gemm_nn(const float* __restrict__ A,
                                               const float* __restrict__ Bg,
                                               float* __restrict__ C) {
    constexpr int K = H, N = H;
    __shared__ float As[32][68];   // [k][m], +4 pad keeps 16B alignment, shifts banks
    __shared__ float Bs[32][68];   // [k][n]

    const int t  = threadIdx.x;
    const int m0 = blockIdx.y * 64;
    const int n0 = blockIdx.x * 64;

    const int aK = (t & 7) << 2;   // 0..28
    const int aR = t >> 3;         // 0..31
    const int bN = (t & 15) << 2;  // 0..60
    const int bK = t >> 4;         // 0..15

    const int tx = t & 15;         // n-dir
    const int ty = t >> 4;         // m-dir

    float acc[4][4];
#pragma unroll
    for (int i = 0; i < 4; ++i)
#pragma unroll
        for (int j = 0; j < 4; ++j) acc[i][j] = 0.f;

    for (int k0 = 0; k0 < K; k0 += 32) {
        // stage A transposed: As[k][m]
#pragma unroll
        for (int r = 0; r < 2; ++r) {
            const int row = aR + 32 * r;
            const float4 v = *reinterpret_cast<const float4*>(
                &A[(size_t)(m0 + row) * K + k0 + aK]);
            As[aK + 0][row] = v.x;
            As[aK + 1][row] = v.y;
            As[aK + 2][row] = v.z;
            As[aK + 3][row] = v.w;
        }
        // stage B direct: Bs[k][n]
#pragma unroll
        for (int r = 0; r < 2; ++r) {
            const int kk = bK + 16 * r;
            *reinterpret_cast<float4*>(&Bs[kk][bN]) =
                *reinterpret_cast<const float4*>(&Bg[(size_t)(k0 + kk) * N + n0 + bN]);
        }
        __syncthreads();

#pragma unroll
        for (int kk = 0; kk < 32; ++kk) {
            const float4 av = *reinterpret_cast<const float4*>(&As[kk][ty << 2]);
            const float4 bv = *reinterpret_cast<const float4*>(&Bs[kk][tx << 2]);
            const float a[4] = {av.x, av.y, av.z, av.w};
            const float b[4] = {bv.x, bv.y, bv.z, bv.w};
#pragma unroll
            for (int i = 0; i < 4; ++i)
#pragma unroll
                for (int j = 0; j < 4; ++j) acc[i][j] += a[i] * b[j];
        }
        __syncthreads();
    }

#pragma unroll
    for (int i = 0; i < 4; ++i) {
        float4 v = make_float4(acc[i][0], acc[i][1], acc[i][2], acc[i][3]);
        *reinterpret_cast<float4*>(
            &C[(size_t)(m0 + (ty << 2) + i) * N + n0 + (tx << 2)]) = v;
    }
}

// ---------------------------------------------------------------------------
// GEMM 2 (NT, batched): E[b][i][j] = sum_k Q[b][i][k] * Hist[b][j][k]
//   per batch: M = S_STATE = 512, N = S_SEQ = 2048, K = H = 512
// Both operands are K-contiguous (NT) -> both staged transposed into LDS.
// ---------------------------------------------------------------------------
__global__ __launch_bounds__(256) void gemm_nt_batched(const float* __restrict__ Q,
                                                       const float* __restrict__ Hist,
                                                       float* __restrict__ E) {
    constexpr int K = H;
    __shared__ float As[32][68];   // [k][i]
    __shared__ float Bs[32][68];   // [k][j]

    const int t  = threadIdx.x;
    const int m0 = blockIdx.y * 64;
    const int n0 = blockIdx.x * 64;
    const int b  = blockIdx.z;

    const float* Qb = Q    + (size_t)b * S_STATE * H;
    const float* Hb = Hist + (size_t)b * S_SEQ   * H;
    float*       Eb = E    + (size_t)b * S_STATE * S_SEQ;

    const int aK = (t & 7) << 2;   // 0..28
    const int aR = t >> 3;         // 0..31

    const int tx = t & 15;         // j-dir
    const int ty = t >> 4;         // i-dir

    float acc[4][4];
#pragma unroll
    for (int i = 0; i < 4; ++i)
#pragma unroll
        for (int j = 0; j < 4; ++j) acc[i][j] = 0.f;

    for (int k0 = 0; k0 < K; k0 += 32) {
#pragma unroll
        for (int r = 0; r < 2; ++r) {
            const int row = aR + 32 * r;
            const float4 v = *reinterpret_cast<const float4*>(
                &Qb[(size_t)(m0 + row) * K + k0 + aK]);
            As[aK + 0][row] = v.x;
            As[aK + 1][row] = v.y;
            As[aK + 2][row] = v.z;
            As[aK + 3][row] = v.w;
        }
#pragma unroll
        for (int r = 0; r < 2; ++r) {
            const int row = aR + 32 * r;
            const float4 v = *reinterpret_cast<const float4*>(
                &Hb[(size_t)(n0 + row) * K + k0 + aK]);
            Bs[aK + 0][row] = v.x;
            Bs[aK + 1][row] = v.y;
            Bs[aK + 2][row] = v.z;
            Bs[aK + 3][row] = v.w;
        }
        __syncthreads();

#pragma unroll
        for (int kk = 0; kk < 32; ++kk) {
            const float4 av = *reinterpret_cast<const float4*>(&As[kk][ty << 2]);
            const float4 bv = *reinterpret_cast<const float4*>(&Bs[kk][tx << 2]);
            const float a[4] = {av.x, av.y, av.z, av.w};
            const float b2[4] = {bv.x, bv.y, bv.z, bv.w};
#pragma unroll
            for (int i = 0; i < 4; ++i)
#pragma unroll
                for (int j = 0; j < 4; ++j) acc[i][j] += a[i] * b2[j];
        }
        __syncthreads();
    }

#pragma unroll
    for (int i = 0; i < 4; ++i) {
        float4 v = make_float4(acc[i][0], acc[i][1], acc[i][2], acc[i][3]);
        *reinterpret_cast<float4*>(
            &Eb[(size_t)(m0 + (ty << 2) + i) * S_SEQ + n0 + (tx << 2)]) = v;
    }
}

// ---------------------------------------------------------------------------
// Softmax over rows of 2048, in place on d_out. One 256-thread block per row.
// ---------------------------------------------------------------------------
__global__ __launch_bounds__(256) void softmax_rows(float* __restrict__ out) {
    const int t = threadIdx.x;
    const size_t base = (size_t)blockIdx.x * S_SEQ;

    float4 v0 = *reinterpret_cast<float4*>(&out[base + (t << 2)]);
    float4 v1 = *reinterpret_cast<float4*>(&out[base + 1024 + (t << 2)]);

    float m = fmaxf(fmaxf(fmaxf(v0.x, v0.y), fmaxf(v0.z, v0.w)),
                    fmaxf(fmaxf(v1.x, v1.y), fmaxf(v1.z, v1.w)));
#pragma unroll
    for (int off = 32; off; off >>= 1) m = fmaxf(m, __shfl_xor(m, off));

    __shared__ float redm[4];
    __shared__ float reds[4];
    if ((t & 63) == 0) redm[t >> 6] = m;
    __syncthreads();
    m = fmaxf(fmaxf(redm[0], redm[1]), fmaxf(redm[2], redm[3]));

    v0.x = __expf(v0.x - m); v0.y = __expf(v0.y - m);
    v0.z = __expf(v0.z - m); v0.w = __expf(v0.w - m);
    v1.x = __expf(v1.x - m); v1.y = __expf(v1.y - m);
    v1.z = __expf(v1.z - m); v1.w = __expf(v1.w - m);

    float s = v0.x + v0.y + v0.z + v0.w + v1.x + v1.y + v1.z + v1.w;
#pragma unroll
    for (int off = 32; off; off >>= 1) s += __shfl_xor(s, off);
    if ((t & 63) == 0) reds[t >> 6] = s;
    __syncthreads();
    s = reds[0] + reds[1] + reds[2] + reds[3];

    const float inv = 1.0f / s;
    v0.x *= inv; v0.y *= inv; v0.z *= inv; v0.w *= inv;
    v1.x *= inv; v1.y *= inv; v1.z *= inv; v1.w *= inv;

    *reinterpret_cast<float4*>(&out[base + (t << 2)]) = v0;
    *reinterpret_cast<float4*>(&out[base + 1024 + (t << 2)]) = v1;
}

extern "C" void kernel_launch(void* const* d_in, const int* in_sizes, int n_in,
                              void* d_out, int out_size, void* d_ws, size_t ws_size,
                              hipStream_t stream) {
    const float* out_state = (const float*)d_in[0]; // [B, S_STATE, H]
    const float* history   = (const float*)d_in[1]; // [B, S_SEQ, H]
    const float* attn_w    = (const float*)d_in[2]; // [H, H]  (W[h][d])
    // attn_b (d_in[3]) intentionally unused: it adds a per-(b,i) constant to the
    // energies, which cancels exactly in the row softmax.

    float* q   = (float*)d_ws;   // [B, S_STATE, H] = 64 MiB scratch
    float* out = (float*)d_out;  // [B, S_STATE, S_SEQ]

    // q[m][d] = sum_h os[m][h] * W[h][d]   (M=32768, N=512, K=512)
    gemm_nn<<<dim3(H / 64, (B * S_STATE) / 64), 256, 0, stream>>>(out_state, attn_w, q);

    // E[b][i][j] = q[b][i][:] . history[b][j][:]
    gemm_nt_batched<<<dim3(S_SEQ / 64, S_STATE / 64, B), 256, 0, stream>>>(q, history, out);

    // softmax over j, in place
    softmax_rows<<<B * S_STATE, 256, 0, stream>>>(out);
}

// Round 2
// 892.092 us; speedup vs baseline: 1.7723x; 1.7723x over previous
//
#include <hip/hip_runtime.h>
#include <math.h>

// energies[b,i,j] = out_state[b,i,:] . (W @ history[b,j,:] + bias); out = softmax_j.
// Restructured:
//   q[b,i,:] = W^T @ out_state[b,i,:]   (project small side; bias cancels in softmax)
//   E[b,i,j] = q[b,i,:] . history[b,j,:]
// Precision: fp32 operands split into bf16 hi+lo; x.y ~= xh.yh + xh.yl + xl.yh
// via MFMA 16x16x32 bf16 with fp32 accumulate (error ~2^-16 rel, threshold 2e-2).
constexpr int B        = 64;
constexpr int S_STATE  = 512;
constexpr int S_SEQ    = 2048;
constexpr int H        = 512;

typedef __attribute__((ext_vector_type(8))) short bf16x8;
typedef __attribute__((ext_vector_type(4))) float f32x4;

static __device__ __forceinline__ unsigned short f2bf(float f) {
    unsigned int u = __float_as_uint(f);
    u = u + 0x7FFFu + ((u >> 16) & 1u);   // RNE
    return (unsigned short)(u >> 16);
}
static __device__ __forceinline__ float bf2f(unsigned short h) {
    return __uint_as_float(((unsigned int)h) << 16);
}

// ---------------------------------------------------------------------------
// Elementwise fp32 -> bf16 hi/lo split. n must be divisible by 4.
// ---------------------------------------------------------------------------
__global__ __launch_bounds__(256) void split_f32(const float* __restrict__ x,
                                                 unsigned short* __restrict__ hi,
                                                 unsigned short* __restrict__ lo,
                                                 size_t n4) {
    size_t i = (size_t)blockIdx.x * 256 + threadIdx.x;
    if (i >= n4) return;
    const float4 v = reinterpret_cast<const float4*>(x)[i];
    ushort4 h, l;
    h.x = f2bf(v.x); l.x = f2bf(v.x - bf2f(h.x));
    h.y = f2bf(v.y); l.y = f2bf(v.y - bf2f(h.y));
    h.z = f2bf(v.z); l.z = f2bf(v.z - bf2f(h.z));
    h.w = f2bf(v.w); l.w = f2bf(v.w - bf2f(h.w));
    reinterpret_cast<ushort4*>(hi)[i] = h;
    reinterpret_cast<ushort4*>(lo)[i] = l;
}

// W[h][d] -> Wt_hi/lo[d][h]  (512x512, tiny)
__global__ __launch_bounds__(256) void split_transpose_w(const float* __restrict__ w,
                                                         unsigned short* __restrict__ thi,
                                                         unsigned short* __restrict__ tlo) {
    int idx = blockIdx.x * 256 + threadIdx.x;     // h*512 + d, d fastest
    int h = idx >> 9, d = idx & 511;
    float v = w[idx];
    unsigned short hh = f2bf(v);
    thi[d * 512 + h] = hh;
    tlo[d * 512 + h] = f2bf(v - bf2f(hh));
}

// ---------------------------------------------------------------------------
// Batched NT GEMM, split-bf16 MFMA:  C[m][n] = sum_k A[m][k] * B[n][k]
// A,B given as bf16 hi/lo pairs, K-contiguous rows. BM=BN=128, BK=32,
// 256 threads = 4 waves, each wave a 64x64 quadrant = 4x4 MFMA 16x16 tiles.
// SPLIT_OUT: write C as bf16 hi/lo (for q); else fp32.
// ---------------------------------------------------------------------------
constexpr int LP = 40;   // LDS row pitch (elements); 80B stride -> 2-way banks max

template <bool SPLIT_OUT>
__global__ __launch_bounds__(256)
void gemm_nt_mfma(const unsigned short* __restrict__ Ahi, const unsigned short* __restrict__ Alo,
                  const unsigned short* __restrict__ Bhi, const unsigned short* __restrict__ Blo,
                  float* __restrict__ Cf, unsigned short* __restrict__ Chi,
                  unsigned short* __restrict__ Clo,
                  int K, int N, size_t aBatch, size_t bBatch, size_t cBatch) {
    __shared__ unsigned short sA[2][128 * LP];   // [hi/lo][row*LP + k]
    __shared__ unsigned short sB[2][128 * LP];

    const int t  = threadIdx.x;
    const int m0 = blockIdx.y * 128;
    const int n0 = blockIdx.x * 128;
    const size_t aOff = (size_t)blockIdx.z * aBatch;
    const size_t bOff = (size_t)blockIdx.z * bBatch;
    const size_t cOff = (size_t)blockIdx.z * cBatch;

    const int lane = t & 63, wv = t >> 6;
    const int wm = wv >> 1, wn = wv & 1;
    const int lrow = lane & 15, quad = lane >> 4;
    const int fko = quad * 8;                    // frag k-offset (8 bf16 = 16B)

    // staging: thread t loads 16B chunks for rows r0 and r0+64, k-offset kk
    const int r0 = t >> 2;                       // 0..63
    const int kk = (t & 3) * 8;                  // 0,8,16,24

    f32x4 acc[4][4];
#pragma unroll
    for (int i = 0; i < 4; ++i)
#pragma unroll
        for (int j = 0; j < 4; ++j) acc[i][j] = (f32x4){0.f, 0.f, 0.f, 0.f};

    for (int k0 = 0; k0 < K; k0 += 32) {
        const size_t ga0 = aOff + (size_t)(m0 + r0) * K + k0 + kk;
        const size_t ga1 = aOff + (size_t)(m0 + r0 + 64) * K + k0 + kk;
        const size_t gb0 = bOff + (size_t)(n0 + r0) * K + k0 + kk;
        const size_t gb1 = bOff + (size_t)(n0 + r0 + 64) * K + k0 + kk;
        const uint4 vAh0 = *reinterpret_cast<const uint4*>(&Ahi[ga0]);
        const uint4 vAh1 = *reinterpret_cast<const uint4*>(&Ahi[ga1]);
        const uint4 vAl0 = *reinterpret_cast<const uint4*>(&Alo[ga0]);
        const uint4 vAl1 = *reinterpret_cast<const uint4*>(&Alo[ga1]);
        const uint4 vBh0 = *reinterpret_cast<const uint4*>(&Bhi[gb0]);
        const uint4 vBh1 = *reinterpret_cast<const uint4*>(&Bhi[gb1]);
        const uint4 vBl0 = *reinterpret_cast<const uint4*>(&Blo[gb0]);
        const uint4 vBl1 = *reinterpret_cast<const uint4*>(&Blo[gb1]);

        __syncthreads();   // previous iteration's frag reads complete
        const int s0 = r0 * LP + kk, s1 = (r0 + 64) * LP + kk;
        *reinterpret_cast<uint4*>(&sA[0][s0]) = vAh0;
        *reinterpret_cast<uint4*>(&sA[0][s1]) = vAh1;
        *reinterpret_cast<uint4*>(&sA[1][s0]) = vAl0;
        *reinterpret_cast<uint4*>(&sA[1][s1]) = vAl1;
        *reinterpret_cast<uint4*>(&sB[0][s0]) = vBh0;
        *reinterpret_cast<uint4*>(&sB[0][s1]) = vBh1;
        *reinterpret_cast<uint4*>(&sB[1][s0]) = vBl0;
        *reinterpret_cast<uint4*>(&sB[1][s1]) = vBl1;
        __syncthreads();

        bf16x8 aH[4], aL[4];
#pragma unroll
        for (int mt = 0; mt < 4; ++mt) {
            const int r = (wm * 64 + mt * 16 + lrow) * LP + fko;
            aH[mt] = *reinterpret_cast<const bf16x8*>(&sA[0][r]);
            aL[mt] = *reinterpret_cast<const bf16x8*>(&sA[1][r]);
        }
#pragma unroll
        for (int nt = 0; nt < 4; ++nt) {
            const int r = (wn * 64 + nt * 16 + lrow) * LP + fko;
            const bf16x8 bH = *reinterpret_cast<const bf16x8*>(&sB[0][r]);
            const bf16x8 bL = *reinterpret_cast<const bf16x8*>(&sB[1][r]);
#pragma unroll
            for (int mt = 0; mt < 4; ++mt) {
                acc[mt][nt] = __builtin_amdgcn_mfma_f32_16x16x32_bf16(aH[mt], bH, acc[mt][nt], 0, 0, 0);
                acc[mt][nt] = __builtin_amdgcn_mfma_f32_16x16x32_bf16(aH[mt], bL, acc[mt][nt], 0, 0, 0);
                acc[mt][nt] = __builtin_amdgcn_mfma_f32_16x16x32_bf16(aL[mt], bH, acc[mt][nt], 0, 0, 0);
            }
        }
    }

    // epilogue: C/D layout col=lane&15, row=quad*4+reg (verified m89/m91)
#pragma unroll
    for (int mt = 0; mt < 4; ++mt) {
#pragma unroll
        for (int nt = 0; nt < 4; ++nt) {
#pragma unroll
            for (int r = 0; r < 4; ++r) {
                const int gi = m0 + wm * 64 + mt * 16 + quad * 4 + r;
                const int gj = n0 + wn * 64 + nt * 16 + lrow;
                const float v = acc[mt][nt][r];
                if constexpr (SPLIT_OUT) {
                    const unsigned short hh = f2bf(v);
                    Chi[cOff + (size_t)gi * N + gj] = hh;
                    Clo[cOff + (size_t)gi * N + gj] = f2bf(v - bf2f(hh));
                } else {
                    Cf[cOff + (size_t)gi * N + gj] = v;
                }
            }
        }
    }
}

// ---------------------------------------------------------------------------
// Softmax over rows of 2048, in place. One 256-thread block per row.
// ---------------------------------------------------------------------------
__global__ __launch_bounds__(256) void softmax_rows(float* __restrict__ out) {
    const int t = threadIdx.x;
    const size_t base = (size_t)blockIdx.x * S_SEQ;

    float4 v0 = *reinterpret_cast<float4*>(&out[base + (t << 2)]);
    float4 v1 = *reinterpret_cast<float4*>(&out[base + 1024 + (t << 2)]);

    float m = fmaxf(fmaxf(fmaxf(v0.x, v0.y), fmaxf(v0.z, v0.w)),
                    fmaxf(fmaxf(v1.x, v1.y), fmaxf(v1.z, v1.w)));
#pragma unroll
    for (int off = 32; off; off >>= 1) m = fmaxf(m, __shfl_xor(m, off));

    __shared__ float redm[4];
    __shared__ float reds[4];
    if ((t & 63) == 0) redm[t >> 6] = m;
    __syncthreads();
    m = fmaxf(fmaxf(redm[0], redm[1]), fmaxf(redm[2], redm[3]));

    v0.x = __expf(v0.x - m); v0.y = __expf(v0.y - m);
    v0.z = __expf(v0.z - m); v0.w = __expf(v0.w - m);
    v1.x = __expf(v1.x - m); v1.y = __expf(v1.y - m);
    v1.z = __expf(v1.z - m); v1.w = __expf(v1.w - m);

    float s = v0.x + v0.y + v0.z + v0.w + v1.x + v1.y + v1.z + v1.w;
#pragma unroll
    for (int off = 32; off; off >>= 1) s += __shfl_xor(s, off);
    if ((t & 63) == 0) reds[t >> 6] = s;
    __syncthreads();
    s = reds[0] + reds[1] + reds[2] + reds[3];

    const float inv = 1.0f / s;
    v0.x *= inv; v0.y *= inv; v0.z *= inv; v0.w *= inv;
    v1.x *= inv; v1.y *= inv; v1.z *= inv; v1.w *= inv;

    *reinterpret_cast<float4*>(&out[base + (t << 2)]) = v0;
    *reinterpret_cast<float4*>(&out[base + 1024 + (t << 2)]) = v1;
}

// ===========================================================================
// fp32 fallback path (round-1 kernels) used only if ws_size is too small.
// ===========================================================================
__global__ __launch_bounds__(256) void gemm_nn(const float* __restrict__ A,
                                               const float* __restrict__ Bg,
                                               float* __restrict__ C) {
    constexpr int K = H, N = H;
    __shared__ float As[32][68];
    __shared__ float Bs[32][68];
    const int t  = threadIdx.x;
    const int m0 = blockIdx.y * 64;
    const int n0 = blockIdx.x * 64;
    const int aK = (t & 7) << 2;
    const int aR = t >> 3;
    const int bN = (t & 15) << 2;
    const int bK = t >> 4;
    const int tx = t & 15;
    const int ty = t >> 4;
    float acc[4][4];
#pragma unroll
    for (int i = 0; i < 4; ++i)
#pragma unroll
        for (int j = 0; j < 4; ++j) acc[i][j] = 0.f;
    for (int k0 = 0; k0 < K; k0 += 32) {
#pragma unroll
        for (int r = 0; r < 2; ++r) {
            const int row = aR + 32 * r;
            const float4 v = *reinterpret_cast<const float4*>(&A[(size_t)(m0 + row) * K + k0 + aK]);
            As[aK + 0][row] = v.x; As[aK + 1][row] = v.y;
            As[aK + 2][row] = v.z; As[aK + 3][row] = v.w;
        }
#pragma unroll
        for (int r = 0; r < 2; ++r) {
            const int kkk = bK + 16 * r;
            *reinterpret_cast<float4*>(&Bs[kkk][bN]) =
                *reinterpret_cast<const float4*>(&Bg[(size_t)(k0 + kkk) * N + n0 + bN]);
        }
        __syncthreads();
#pragma unroll
        for (int kkk = 0; kkk < 32; ++kkk) {
            const float4 av = *reinterpret_cast<const float4*>(&As[kkk][ty << 2]);
            const float4 bv = *reinterpret_cast<const float4*>(&Bs[kkk][tx << 2]);
            const float a[4] = {av.x, av.y, av.z, av.w};
            const float b[4] = {bv.x, bv.y, bv.z, bv.w};
#pragma unroll
            for (int i = 0; i < 4; ++i)
#pragma unroll
                for (int j = 0; j < 4; ++j) acc[i][j] += a[i] * b[j];
        }
        __syncthreads();
    }
#pragma unroll
    for (int i = 0; i < 4; ++i) {
        float4 v = make_float4(acc[i][0], acc[i][1], acc[i][2], acc[i][3]);
        *reinterpret_cast<float4*>(&C[(size_t)(m0 + (ty << 2) + i) * N + n0 + (tx << 2)]) = v;
    }
}

__global__ __launch_bounds__(256) void gemm_nt_batched(const float* __restrict__ Q,
                                                       const float* __restrict__ Hist,
                                                       float* __restrict__ E) {
    constexpr int K = H;
    __shared__ float As[32][68];
    __shared__ float Bs[32][68];
    const int t  = threadIdx.x;
    const int m0 = blockIdx.y * 64;
    const int n0 = blockIdx.x * 64;
    const int b  = blockIdx.z;
    const float* Qb = Q    + (size_t)b * S_STATE * H;
    const float* Hb = Hist + (size_t)b * S_SEQ   * H;
    float*       Eb = E    + (size_t)b * S_STATE * S_SEQ;
    const int aK = (t & 7) << 2;
    const int aR = t >> 3;
    const int tx = t & 15;
    const int ty = t >> 4;
    float acc[4][4];
#pragma unroll
    for (int i = 0; i < 4; ++i)
#pragma unroll
        for (int j = 0; j < 4; ++j) acc[i][j] = 0.f;
    for (int k0 = 0; k0 < K; k0 += 32) {
#pragma unroll
        for (int r = 0; r < 2; ++r) {
            const int row = aR + 32 * r;
            const float4 v = *reinterpret_cast<const float4*>(&Qb[(size_t)(m0 + row) * K + k0 + aK]);
            As[aK + 0][row] = v.x; As[aK + 1][row] = v.y;
            As[aK + 2][row] = v.z; As[aK + 3][row] = v.w;
        }
#pragma unroll
        for (int r = 0; r < 2; ++r) {
            const int row = aR + 32 * r;
            const float4 v = *reinterpret_cast<const float4*>(&Hb[(size_t)(n0 + row) * K + k0 + aK]);
            Bs[aK + 0][row] = v.x; Bs[aK + 1][row] = v.y;
            Bs[aK + 2][row] = v.z; Bs[aK + 3][row] = v.w;
        }
        __syncthreads();
#pragma unroll
        for (int kkk = 0; kkk < 32; ++kkk) {
            const float4 av = *reinterpret_cast<const float4*>(&As[kkk][ty << 2]);
            const float4 bv = *reinterpret_cast<const float4*>(&Bs[kkk][tx << 2]);
            const float a[4] = {av.x, av.y, av.z, av.w};
            const float b2[4] = {bv.x, bv.y, bv.z, bv.w};
#pragma unroll
            for (int i = 0; i < 4; ++i)
#pragma unroll
                for (int j = 0; j < 4; ++j) acc[i][j] += a[i] * b2[j];
        }
        __syncthreads();
    }
#pragma unroll
    for (int i = 0; i < 4; ++i) {
        float4 v = make_float4(acc[i][0], acc[i][1], acc[i][2], acc[i][3]);
        *reinterpret_cast<float4*>(&Eb[(size_t)(m0 + (ty << 2) + i) * S_SEQ + n0 + (tx << 2)]) = v;
    }
}

// ===========================================================================
extern "C" void kernel_launch(void* const* d_in, const int* in_sizes, int n_in,
                              void* d_out, int out_size, void* d_ws, size_t ws_size,
                              hipStream_t stream) {
    const float* out_state = (const float*)d_in[0]; // [B, S_STATE, H]
    const float* history   = (const float*)d_in[1]; // [B, S_SEQ, H]
    const float* attn_w    = (const float*)d_in[2]; // [H, H]
    // attn_b (d_in[3]) unused: constant along softmax axis -> cancels exactly.
    float* out = (float*)d_out;

    // ws partition (bf16 split arrays), 256B aligned
    const size_t nOS = (size_t)B * S_STATE * H;      // 16.7M
    const size_t nH  = (size_t)B * S_SEQ * H;        // 67.1M
    const size_t nW  = (size_t)H * H;
    size_t off = 0;
    auto alloc = [&](size_t bytes) { size_t o = off; off = (off + bytes + 255) & ~(size_t)255; return o; };
    char* ws = (char*)d_ws;
    const size_t o_osh = alloc(nOS * 2), o_osl = alloc(nOS * 2);
    const size_t o_wth = alloc(nW * 2),  o_wtl = alloc(nW * 2);
    const size_t o_qh  = alloc(nOS * 2), o_ql  = alloc(nOS * 2);
    const size_t o_hh  = alloc(nH * 2),  o_hl  = alloc(nH * 2);
    const size_t need = off;

    if (ws_size >= need) {
        unsigned short* os_h = (unsigned short*)(ws + o_osh);
        unsigned short* os_l = (unsigned short*)(ws + o_osl);
        unsigned short* wt_h = (unsigned short*)(ws + o_wth);
        unsigned short* wt_l = (unsigned short*)(ws + o_wtl);
        unsigned short* q_h  = (unsigned short*)(ws + o_qh);
        unsigned short* q_l  = (unsigned short*)(ws + o_ql);
        unsigned short* h_h  = (unsigned short*)(ws + o_hh);
        unsigned short* h_l  = (unsigned short*)(ws + o_hl);

        split_f32<<<(int)(nOS / 4 / 256), 256, 0, stream>>>(out_state, os_h, os_l, nOS / 4);
        split_f32<<<(int)(nH / 4 / 256), 256, 0, stream>>>(history, h_h, h_l, nH / 4);
        split_transpose_w<<<(int)(nW / 256), 256, 0, stream>>>(attn_w, wt_h, wt_l);

        // q[m][d] = sum_k os[m][k] * Wt[d][k]   (M=32768, N=512, K=512)
        gemm_nt_mfma<true><<<dim3(H / 128, (B * S_STATE) / 128, 1), 256, 0, stream>>>(
            os_h, os_l, wt_h, wt_l, nullptr, q_h, q_l, H, H, 0, 0, 0);

        // E[b][i][j] = sum_k q[b][i][k] * hist[b][j][k]
        gemm_nt_mfma<false><<<dim3(S_SEQ / 128, S_STATE / 128, B), 256, 0, stream>>>(
            q_h, q_l, h_h, h_l, out, nullptr, nullptr, H, S_SEQ,
            (size_t)S_STATE * H, (size_t)S_SEQ * H, (size_t)S_STATE * S_SEQ);

        softmax_rows<<<B * S_STATE, 256, 0, stream>>>(out);
    } else {
        // fp32 fallback (round-1 path), needs 64 MiB ws
        float* q = (float*)d_ws;
        gemm_nn<<<dim3(H / 64, (B * S_STATE) / 64), 256, 0, stream>>>(out_state, attn_w, q);
        gemm_nt_batched<<<dim3(S_SEQ / 64, S_STATE / 64, B), 256, 0, stream>>>(q, history, out);
        softmax_rows<<<B * S_STATE, 256, 0, stream>>>(out);
    }
}